// Round 4
// baseline (50.305 us; speedup 1.0000x reference)
//
#include <hip/hip_runtime.h>

#define BINS 10
#define TPB  256
#define NBLK 2048
#define TPB2 1024

// Per-row math using C=2 structure:
//   softmax(pred)[wrong] == sigmoid(d), d = (t==0) ? p1-p0 : p0-p1
//   bce_i = softplus(x_i),  x0 = (t==0)?-p0:p0,  x1 = (t==0)?p1:-p1,  d = x0+x1
//   e0=exp(x0), e1=exp(x1) -> m=e0*e1=exp(d), g = m/(1+m)
//   wsum = log((v0?1+e0:1)*(v1?1+e1:1))   (one log for both elements)
__device__ __forceinline__ void ghm_row(float p0, float p1, int t, float w0, float w1,
                                        float* __restrict__ s, float* __restrict__ c)
{
    bool tz = (t == 0);
    float x0 = tz ? -p0 : p0;
    float x1 = tz ?  p1 : -p1;
    float e0 = __expf(x0);
    float e1 = __expf(x1);
    float m  = e0 * e1;
    float g  = __fdividef(m, 1.0f + m);
    int bin  = min((int)(g * 10.0f), BINS - 1);

    bool v0 = (w0 > 0.0f);
    bool v1 = (w1 > 0.0f);
    float a = v0 ? (1.0f + e0) : 1.0f;
    float b = v1 ? (1.0f + e1) : 1.0f;
    float wsum = __logf(a * b);
    float cntf = (v0 ? 1.0f : 0.0f) + (v1 ? 1.0f : 0.0f);

#pragma unroll
    for (int k = 0; k < BINS; ++k) {
        float mk = (bin == k) ? 1.0f : 0.0f;
        s[k] = fmaf(mk, wsum, s[k]);
        c[k] = fmaf(mk, cntf, c[k]);
    }
}

__global__ __launch_bounds__(TPB) void ghm_stage1(
    const float* __restrict__ pred, const int* __restrict__ target,
    const float* __restrict__ lw, float2* __restrict__ partial, int B)
{
    float s[BINS], c[BINS];
#pragma unroll
    for (int b = 0; b < BINS; ++b) { s[b] = 0.0f; c[b] = 0.0f; }

    const float4* p4 = (const float4*)pred;
    const float4* w4 = (const float4*)lw;
    const int2*   t2 = (const int2*)target;
    const int npairs = B >> 1;
    const int tid = threadIdx.x;

    if (npairs == (int)gridDim.x * (TPB * 8)) {
        // exact-fit path: each block owns 2048 contiguous float4-pairs,
        // 4 iterations x 512 pairs, software-pipelined double buffer.
        const int tile = blockIdx.x * (TPB * 8);
        float4 pb[2][2], wb[2][2];
        int2   tb[2][2];

        int j0 = tile + tid;
        pb[0][0] = p4[j0]; pb[0][1] = p4[j0 + TPB];
        wb[0][0] = w4[j0]; wb[0][1] = w4[j0 + TPB];
        tb[0][0] = t2[j0]; tb[0][1] = t2[j0 + TPB];

#pragma unroll
        for (int i = 0; i < 4; ++i) {
            const int cur = i & 1, nxt = cur ^ 1;
            if (i < 3) {
                int jn = tile + (i + 1) * (2 * TPB) + tid;
                pb[nxt][0] = p4[jn]; pb[nxt][1] = p4[jn + TPB];
                wb[nxt][0] = w4[jn]; wb[nxt][1] = w4[jn + TPB];
                tb[nxt][0] = t2[jn]; tb[nxt][1] = t2[jn + TPB];
            }
            ghm_row(pb[cur][0].x, pb[cur][0].y, tb[cur][0].x, wb[cur][0].x, wb[cur][0].y, s, c);
            ghm_row(pb[cur][0].z, pb[cur][0].w, tb[cur][0].y, wb[cur][0].z, wb[cur][0].w, s, c);
            ghm_row(pb[cur][1].x, pb[cur][1].y, tb[cur][1].x, wb[cur][1].x, wb[cur][1].y, s, c);
            ghm_row(pb[cur][1].z, pb[cur][1].w, tb[cur][1].y, wb[cur][1].z, wb[cur][1].w, s, c);
        }
    } else {
        // generic fallback (not hit for this problem's shape)
        const int stride = gridDim.x * blockDim.x;
        for (int i = blockIdx.x * blockDim.x + tid; i < npairs; i += stride) {
            float4 p = p4[i];
            float4 w = w4[i];
            int2   t = t2[i];
            ghm_row(p.x, p.y, t.x, w.x, w.y, s, c);
            ghm_row(p.z, p.w, t.y, w.z, w.w, s, c);
        }
        if ((B & 1) && blockIdx.x == 0 && tid == 0) {
            int r = B - 1;
            ghm_row(pred[2 * r], pred[2 * r + 1], target[r], lw[2 * r], lw[2 * r + 1], s, c);
        }
    }

    // wave reduce
#pragma unroll
    for (int b = 0; b < BINS; ++b) {
#pragma unroll
        for (int off = 32; off > 0; off >>= 1) {
            s[b] += __shfl_down(s[b], off);
            c[b] += __shfl_down(c[b], off);
        }
    }

    __shared__ float ss[4][BINS];
    __shared__ float sc[4][BINS];
    const int wid  = tid >> 6;
    const int lane = tid & 63;
    if (lane == 0) {
#pragma unroll
        for (int b = 0; b < BINS; ++b) { ss[wid][b] = s[b]; sc[wid][b] = c[b]; }
    }
    __syncthreads();

    if (tid < BINS) {
        int b = tid;
        float S = ss[0][b] + ss[1][b] + ss[2][b] + ss[3][b];
        float C = sc[0][b] + sc[1][b] + sc[2][b] + sc[3][b];
        partial[blockIdx.x * BINS + b] = make_float2(S, C);
    }
}

__global__ __launch_bounds__(TPB2) void ghm_stage2(
    const float2* __restrict__ partial, float* __restrict__ out, int nb)
{
    double dsum[BINS], dcnt[BINS];
#pragma unroll
    for (int b = 0; b < BINS; ++b) { dsum[b] = 0.0; dcnt[b] = 0.0; }

    for (int i = threadIdx.x; i < nb; i += TPB2) {
#pragma unroll
        for (int b = 0; b < BINS; ++b) {
            float2 p = partial[i * BINS + b];
            dsum[b] += (double)p.x;
            dcnt[b] += (double)p.y;
        }
    }

#pragma unroll
    for (int b = 0; b < BINS; ++b) {
        for (int off = 32; off > 0; off >>= 1) {
            dsum[b] += __shfl_down(dsum[b], off);
            dcnt[b] += __shfl_down(dcnt[b], off);
        }
    }

    __shared__ double ss[TPB2 / 64][BINS];
    __shared__ double sc[TPB2 / 64][BINS];
    const int wid  = threadIdx.x >> 6;
    const int lane = threadIdx.x & 63;
    if (lane == 0) {
#pragma unroll
        for (int b = 0; b < BINS; ++b) { ss[wid][b] = dsum[b]; sc[wid][b] = dcnt[b]; }
    }
    __syncthreads();

    if (threadIdx.x == 0) {
        double loss = 0.0;
        int n = 0;
        for (int b = 0; b < BINS; ++b) {
            double S = 0.0, C = 0.0;
            for (int w = 0; w < TPB2 / 64; ++w) { S += ss[w][b]; C += sc[w][b]; }
            if (C > 0.0) { ++n; loss += S / C; }
        }
        if (n == 0) n = 1;
        out[0] = (float)(loss / (double)n);
    }
}

extern "C" void kernel_launch(void* const* d_in, const int* in_sizes, int n_in,
                              void* d_out, int out_size, void* d_ws, size_t ws_size,
                              hipStream_t stream)
{
    const float* pred   = (const float*)d_in[0];
    const int*   target = (const int*)d_in[1];
    const float* lw     = (const float*)d_in[2];
    const int B = in_sizes[1];

    int nb = NBLK;
    size_t need = (size_t)nb * BINS * sizeof(float2);
    if (ws_size < need) nb = (int)(ws_size / (BINS * sizeof(float2)));

    float2* partial = (float2*)d_ws;

    ghm_stage1<<<nb, TPB, 0, stream>>>(pred, target, lw, partial, B);
    ghm_stage2<<<1, TPB2, 0, stream>>>(partial, (float*)d_out, nb);
}

// Round 5
// 40.652 us; speedup vs baseline: 1.2375x; 1.2375x over previous
//
#include <hip/hip_runtime.h>

#define BINS 10
#define TPB  256
#define NBLK 2048
#define NCOPY 16

// Packed per-bin accumulator: bits [48:63] = valid count, bits [0:47] = bce sum
// fixed-point 2^20. Per-copy bounds (16 lanes, <=16 rows/lane/block):
//   count <= 512 < 2^16 ; sum <= 512 * ~13 * 2^20 < 2^33 << 2^48. No carry.
//
// C=2 algebra (proven exact in R4): with x0=(t==0?-p0:p0), x1=(t==0?p1:-p1):
//   g = m/(1+m), m = e0*e1 = exp(x0+x1)   (== |softmax - onehot| for both elems)
//   bce0+bce1 (valid-masked) = log( (v0?1+e0:1) * (v1?1+e1:1) )
__device__ __forceinline__ unsigned long long ghm_pack(float p0, float p1, int t,
                                                       float w0, float w1, int* bin)
{
    bool tz = (t == 0);
    float x0 = tz ? -p0 : p0;
    float x1 = tz ?  p1 : -p1;
    float e0 = __expf(x0);
    float e1 = __expf(x1);
    float m  = e0 * e1;
    float g  = __fdividef(m, 1.0f + m);
    *bin = min((int)(g * 10.0f), BINS - 1);

    bool v0 = (w0 > 0.0f);
    bool v1 = (w1 > 0.0f);
    float a = v0 ? (1.0f + e0) : 1.0f;
    float b = v1 ? (1.0f + e1) : 1.0f;
    float wsum = __logf(a * b);
    unsigned long long cnt = (unsigned long long)((int)v0 + (int)v1);
    return (cnt << 48) | (unsigned long long)(unsigned int)(wsum * 1048576.0f + 0.5f);
}

__device__ __forceinline__ void ghm_2rows(float4 p, int2 t, float4 w,
                                          unsigned long long* hrow)
{
    int b0, b1;
    unsigned long long c0 = ghm_pack(p.x, p.y, t.x, w.x, w.y, &b0);
    unsigned long long c1 = ghm_pack(p.z, p.w, t.y, w.z, w.w, &b1);
    if (b0 == b1) {
        unsigned long long cs = c0 + c1;
        if (cs) atomicAdd(&hrow[b0], cs);
    } else {
        if (c0) atomicAdd(&hrow[b0], c0);
        if (c1) atomicAdd(&hrow[b1], c1);
    }
}

__global__ __launch_bounds__(TPB) void ghm_stage1(
    const float* __restrict__ pred, const int* __restrict__ target,
    const float* __restrict__ lw, unsigned long long* __restrict__ partial, int B)
{
    __shared__ unsigned long long h[NCOPY][BINS];
    for (int k = threadIdx.x; k < NCOPY * BINS; k += TPB)
        ((unsigned long long*)h)[k] = 0ULL;
    __syncthreads();

    // wave w owns copies 4w..4w+3; 16 consecutive lanes share one copy.
    unsigned long long* hrow = h[threadIdx.x >> 4];

    const float4* p4 = (const float4*)pred;
    const float4* w4 = (const float4*)lw;
    const int2*   t2 = (const int2*)target;
    const int npairs = B >> 1;
    const int stride = (int)gridDim.x * TPB;
    int i = blockIdx.x * TPB + threadIdx.x;

    // unroll-by-4, straight-line: all 12 loads issued before any use -> MLP.
    for (; i + 3 * stride < npairs; i += 4 * stride) {
        float4 pa = p4[i];
        float4 pb = p4[i + stride];
        float4 pc = p4[i + 2 * stride];
        float4 pd = p4[i + 3 * stride];
        float4 wa = w4[i];
        float4 wb = w4[i + stride];
        float4 wc = w4[i + 2 * stride];
        float4 wd = w4[i + 3 * stride];
        int2   ta = t2[i];
        int2   tb = t2[i + stride];
        int2   tc = t2[i + 2 * stride];
        int2   td = t2[i + 3 * stride];
        ghm_2rows(pa, ta, wa, hrow);
        ghm_2rows(pb, tb, wb, hrow);
        ghm_2rows(pc, tc, wc, hrow);
        ghm_2rows(pd, td, wd, hrow);
    }
    for (; i < npairs; i += stride)
        ghm_2rows(p4[i], t2[i], w4[i], hrow);

    if ((B & 1) && blockIdx.x == 0 && threadIdx.x == 0) {
        int r = B - 1;
        int bb;
        unsigned long long cc = ghm_pack(pred[2 * r], pred[2 * r + 1], target[r],
                                         lw[2 * r], lw[2 * r + 1], &bb);
        if (cc) atomicAdd(&h[0][bb], cc);
    }
    __syncthreads();

    if (threadIdx.x < BINS) {
        unsigned long long v = 0;
#pragma unroll
        for (int c = 0; c < NCOPY; ++c) v += h[c][threadIdx.x];
        partial[blockIdx.x * BINS + threadIdx.x] = v;
    }
}

__global__ __launch_bounds__(TPB) void ghm_stage2(
    const unsigned long long* __restrict__ partial, float* __restrict__ out, int nb)
{
    double dsum[BINS], dcnt[BINS];
#pragma unroll
    for (int b = 0; b < BINS; ++b) { dsum[b] = 0.0; dcnt[b] = 0.0; }

    for (int i = threadIdx.x; i < nb; i += TPB) {
#pragma unroll
        for (int b = 0; b < BINS; ++b) {
            unsigned long long p = partial[i * BINS + b];
            dcnt[b] += (double)(p >> 48);
            dsum[b] += (double)(p & ((1ULL << 48) - 1)) * (1.0 / 1048576.0);
        }
    }

#pragma unroll
    for (int b = 0; b < BINS; ++b) {
        for (int off = 32; off > 0; off >>= 1) {
            dsum[b] += __shfl_down(dsum[b], off);
            dcnt[b] += __shfl_down(dcnt[b], off);
        }
    }

    __shared__ double ss[4][BINS];
    __shared__ double sc[4][BINS];
    const int wid  = threadIdx.x >> 6;
    const int lane = threadIdx.x & 63;
    if (lane == 0) {
#pragma unroll
        for (int b = 0; b < BINS; ++b) { ss[wid][b] = dsum[b]; sc[wid][b] = dcnt[b]; }
    }
    __syncthreads();

    if (threadIdx.x == 0) {
        double loss = 0.0;
        int n = 0;
        for (int b = 0; b < BINS; ++b) {
            double S = ss[0][b] + ss[1][b] + ss[2][b] + ss[3][b];
            double C = sc[0][b] + sc[1][b] + sc[2][b] + sc[3][b];
            if (C > 0.0) { ++n; loss += S / C; }
        }
        if (n == 0) n = 1;
        out[0] = (float)(loss / (double)n);
    }
}

extern "C" void kernel_launch(void* const* d_in, const int* in_sizes, int n_in,
                              void* d_out, int out_size, void* d_ws, size_t ws_size,
                              hipStream_t stream)
{
    const float* pred   = (const float*)d_in[0];
    const int*   target = (const int*)d_in[1];
    const float* lw     = (const float*)d_in[2];
    const int B = in_sizes[1];

    int nb = NBLK;
    size_t need = (size_t)nb * BINS * sizeof(unsigned long long);
    if (ws_size < need) nb = (int)(ws_size / (BINS * sizeof(unsigned long long)));

    unsigned long long* partial = (unsigned long long*)d_ws;

    ghm_stage1<<<nb, TPB, 0, stream>>>(pred, target, lw, partial, B);
    ghm_stage2<<<1, TPB, 0, stream>>>(partial, (float*)d_out, nb);
}